// Round 5
// baseline (270.978 us; speedup 1.0000x reference)
//
#include <hip/hip_runtime.h>
#include <math.h>

#define KK 48
#define TT 1024
#define BB 512
#define START_TAG 46
#define END_TAG 47
#define NSEG 8
#define OWN (TT / NSEG)     // 128 owned steps per segment wave
#define WARM 16             // warm-up steps for segments 1..7 (direction mixing)
#define NTHR (NSEG * 64)

typedef _Float16 h2 __attribute__((ext_vector_type(2)));

#if defined(__has_builtin)
#if __has_builtin(__builtin_amdgcn_fdot2)
#define HAVE_FDOT2 1
#endif
#endif

// v_dot2_f32_f16: c + a.x*b.x + a.y*b.y (f32 accumulate)
__device__ __forceinline__ float fdot2(h2 a, h2 b, float c) {
#ifdef HAVE_FDOT2
    return __builtin_amdgcn_fdot2(a, b, c, false);
#else
    return c + (float)a.x * (float)b.x + (float)a.y * (float)b.y;
#endif
}

// ---------------------------------------------------------------------------
// R14: ds_bpermute broadcast replaces the 24-readlane broadcast (R12 skeleton).
//
// R12 (NSEG=8, 4 waves/SIMD, readlane broadcast): 95.6 us, VALUBusy 64%,
// measured VALU issue ~255 cyc/step vs ~140 static -> the 24 v_readlane are
// the excess (~4 cyc each; R9 noted stall scales with readlane count).
// R13's LDS-memory broadcast hit the int*/i4* aliasing trap (reads hoisted
// past stores -> stale state -> inf). R14 uses the crossbar instead:
// 24x ds_bpermute_b32 (register-based, LDS pipe, no memory, no aliasing).
// All lanes pass index 8c -> receive lane 2c's pkb; result is wave-uniform
// in a VGPR, consumed directly by v_dot2_f32_f16. Broadcast dwords are
// bit-identical to R12 -> numerics/ledger unchanged. Index VGPRs derived
// from an opaque mbcnt-zero so they stay VGPR-resident and hoist.
// Predicted: VALU issue/step 255 -> ~150 cyc; dur 55-75 us; VALUBusy
// 50-60%; VGPR ~100 (4 waves/SIMD kept); bank conflicts 0; absmax 32.
// ---------------------------------------------------------------------------

template <bool EXACT>
__device__ __forceinline__ void run_seg(const float* __restrict__ fb,
                                        const float* __restrict__ trans,
                                        int ci, bool evenLane,
                                        int r0, int ngrp,
                                        float& sOut, int& oOut, float& q0Out) {
    // E rows in f16 pairs: Eh[c] = (exp(trans[ci][2c]), exp(trans[ci][2c+1]))
    h2 Eh[24];
    #pragma unroll
    for (int c = 0; c < 24; ++c) {
        float e0 = __expf(trans[ci * KK + 2 * c]);
        float e1 = __expf(trans[ci * KK + 2 * c + 1]);
        Eh[c] = (h2){(_Float16)e0, (_Float16)e1};
    }

    // opaque zero in a VGPR (mbcnt not constant-foldable) -> bpermute byte
    // indices live in VGPRs and hoist out of the loop as loop invariants
    int lzero = (int)(__builtin_amdgcn_mbcnt_lo(~0u, 0u) & ~63u);
    int bidx[24];
    #pragma unroll
    for (int c = 0; c < 24; ++c) bidx[c] = lzero + 8 * c;  // lane 2c, byte addr

    // packed-f16 broadcast state in VGPRs (wave-uniform content)
    int au[24];
    #pragma unroll
    for (int c = 0; c < 24; ++c)
        au[c] = EXACT ? ((c == 23) ? 0x00003C00 : 0)   // e_START pack
                      : 0x3C003C00;                    // all-ones

    float s = 0.0f;
    int esum = 0;
    int eswm = 0;        // ledger at warm-up boundary (0 for EXACT)
    float q0 = 1.0f;     // lane-0 residual at warm-up boundary (unused EXACT)

    // feats prefetch: groups of 4 rows
    float fr[4];
    #pragma unroll
    for (int k = 0; k < 4; ++k) fr[k] = fb[(r0 + k) * KK + ci];

    const int WG = WARM / 4;
    for (int g = 0; g < ngrp; ++g) {
        float fn[4] = {0.f, 0.f, 0.f, 0.f};
        if (g < ngrp - 1) {
            #pragma unroll
            for (int k = 0; k < 4; ++k)
                fn[k] = fb[(r0 + (g + 1) * 4 + k) * KK + ci];
        }
        float ef[4];
        #pragma unroll
        for (int k = 0; k < 4; ++k) ef[k] = __expf(fr[k]);

        #pragma unroll
        for (int k = 0; k < 4; ++k) {
            // s_i = sum_c dot2(Eh[c], au[c]) : 4 chains x 6 (all-VGPR operands)
            float a0 = 0.f, a1 = 0.f, a2 = 0.f, a3 = 0.f;
            #pragma unroll
            for (int c = 0; c < 6; ++c) {
                a0 = fdot2(Eh[4 * c + 0], __builtin_bit_cast(h2, au[4 * c + 0]), a0);
                a1 = fdot2(Eh[4 * c + 1], __builtin_bit_cast(h2, au[4 * c + 1]), a1);
                a2 = fdot2(Eh[4 * c + 2], __builtin_bit_cast(h2, au[4 * c + 2]), a2);
                a3 = fdot2(Eh[4 * c + 3], __builtin_bit_cast(h2, au[4 * c + 3]), a3);
            }
            float sr = ((a0 + a1) + (a2 + a3)) * ef[k];
            // uniform pow-2 rescale EVERY step (f16 range), exact int ledger
            int rl0 = __builtin_amdgcn_readlane(__float_as_int(sr), 0);
            int e0 = ((rl0 >> 23) & 0xff) - 127;
            esum += e0;
            s = sr * __int_as_float((127 - e0) << 23);
            // pack pair {s_2c, s_2c+1} via DPP partner swap
            int pb = __builtin_amdgcn_update_dpp(
                0, __float_as_int(s), 0xB1, 0xF, 0xF, true);  // quad_perm 1,0,3,2
            float pv = __int_as_float(pb);
            float lo = evenLane ? s : pv;
            float hi = evenLane ? pv : s;
            int pkb = __builtin_bit_cast(int, __builtin_amdgcn_cvt_pkrtz(lo, hi));
            // broadcast via register crossbar: lane 2c's pkb -> all lanes
            #pragma unroll
            for (int c = 0; c < 24; ++c)
                au[c] = __builtin_amdgcn_ds_bpermute(bidx[c], pkb);
        }

        if (!EXACT && g == WG - 1) {   // wave-uniform, taken once
            eswm = esum;
            q0 = __int_as_float(__builtin_amdgcn_readfirstlane(__float_as_int(s)));
        }

        #pragma unroll
        for (int k = 0; k < 4; ++k) fr[k] = fn[k];
    }
    sOut = s;                // residual direction at segment end (lane0 in [1,2))
    oOut = esum - eswm;      // exact owned-steps ledger
    q0Out = q0;
}

__global__ __launch_bounds__(NTHR)
__attribute__((amdgpu_waves_per_eu(4)))
void crf_kernel(const float* __restrict__ feats,
                const float* __restrict__ trans,
                const int* __restrict__ tags,
                float* __restrict__ out) {
    const int b = blockIdx.x;
    const int tid = threadIdx.x;
    const int wave = tid >> 6;          // segment index 0..NSEG-1
    const int lane = tid & 63;
    const int ci = (lane < KK) ? lane : 0;
    const bool evenLane = (lane & 1) == 0;
    const float* fb = feats + (size_t)b * TT * KK;
    const int* tg = tags + b * TT;

    __shared__ float shU[NSEG][64];   // final residual vectors
    __shared__ int shO[NSEG];         // owned ledgers
    __shared__ float shQ0[NSEG];      // lane-0 residual at warm-up boundary
    __shared__ float shGp[NSEG];      // gold partials

    float sF; int oW; float q0;
    if (wave == 0) run_seg<true >(fb, trans, ci, evenLane, 0, OWN / 4, sF, oW, q0);
    else           run_seg<false>(fb, trans, ci, evenLane,
                                  wave * OWN - WARM, (OWN + WARM) / 4, sF, oW, q0);

    shU[wave][lane] = sF;
    if (lane == 0) { shO[wave] = oW; shQ0[wave] = q0; }

    // ---- gold gather: 1024 t's over NTHR threads (after the hot loop) ----
    float gacc = 0.0f;
    #pragma unroll
    for (int r = 0; r < TT / NTHR; ++r) {
        int t = tid + r * NTHR;
        int cur = tg[t];
        int prev = (t == 0) ? START_TAG : tg[t - 1];
        gacc += trans[cur * KK + prev] + fb[(size_t)t * KK + cur];
    }
    #pragma unroll
    for (int off = 32; off; off >>= 1) gacc += __shfl_xor(gacc, off, 64);
    if (lane == 0) shGp[wave] = gacc;

    __syncthreads();

    if (tid < 64) {
        // Z-direction combine: sum_i exp(trans[END][i]) * u_{NSEG-1}[i]
        float val = (lane < KK) ? __expf(trans[END_TAG * KK + lane]) * shU[NSEG - 1][lane]
                                : 0.0f;
        #pragma unroll
        for (int off = 32; off; off >>= 1) val += __shfl_xor(val, off, 64);
        if (lane == 0) {
            int osum = 0;
            float gold = trans[END_TAG * KK + tg[TT - 1]];
            #pragma unroll
            for (int w = 0; w < NSEG; ++w) { osum += shO[w]; gold += shGp[w]; }
            float logz = __logf(val) + (float)osum * 0.6931471805599453f;
            // scalar stitches: alpha scale handoff across segment boundaries
            #pragma unroll
            for (int w = 1; w < NSEG; ++w)
                logz += __logf(shU[w - 1][0]) - __logf(shQ0[w]);
            out[b] = logz - gold;
        }
    }
}

extern "C" void kernel_launch(void* const* d_in, const int* in_sizes, int n_in,
                              void* d_out, int out_size, void* d_ws, size_t ws_size,
                              hipStream_t stream) {
    const float* feats = (const float*)d_in[0];
    const float* trans = (const float*)d_in[1];
    const int* tags = (const int*)d_in[2];
    float* out = (float*)d_out;

    crf_kernel<<<BB, NTHR, 0, stream>>>(feats, trans, tags, out);
}

// Round 6
// 198.982 us; speedup vs baseline: 1.3618x; 1.3618x over previous
//
#include <hip/hip_runtime.h>
#include <math.h>

#define KK 48
#define TT 1024
#define BB 512
#define START_TAG 46
#define END_TAG 47
#define NSEG 16
#define OWN (TT / NSEG)     // 64 owned steps per segment wave
#define WARM 12             // warm-up steps for segments 1..15 (direction mixing)
#define NTHR (NSEG * 64)    // 1024 threads = 16 waves per block

typedef _Float16 h2 __attribute__((ext_vector_type(2)));

#if defined(__has_builtin)
#if __has_builtin(__builtin_amdgcn_fdot2)
#define HAVE_FDOT2 1
#endif
#endif

// v_dot2_f32_f16: c + a.x*b.x + a.y*b.y (f32 accumulate)
__device__ __forceinline__ float fdot2(h2 a, h2 b, float c) {
#ifdef HAVE_FDOT2
    return __builtin_amdgcn_fdot2(a, b, c, false);
#else
    return c + (float)a.x * (float)b.x + (float)a.y * (float)b.y;
#endif
}

// ---------------------------------------------------------------------------
// R15: R12's proven readlane datapath, NSEG 8->16 (8 waves/SIMD), WARM 16->12.
//
// Mechanism ledger: readlane broadcast = 95.6 us @4 waves (R12, VALUBusy 64%);
// LDS-memory broadcast = inf (R10/R13 aliasing traps); ds_bpermute = 170 us
// (R14: 24 bpermutes/step serialize the DS pipe ON the dependency chain).
// Readlane is the cheapest correct broadcast; the remaining lever is filling
// the idle 35% issue capacity. NSEG=16: 8192 waves = 8/SIMD -> issue demand
// 8x255 ~ 2040 cyc/window > 1593 chain -> issue-bound, VALUBusy -> ~100%.
// WARM=12: contraction <=0.46/step -> ~1e-4 direction err/boundary, x15
// boundaries ~ 0.002 in logZ (f16-E systematic absmax 32 dominates; thr 90).
// Per-step datapath byte-identical to R9/R11/R12.
// Predicted: 76 steps x 2040 cyc ~ 65 us dispatch; Occupancy ~70%; absmax 32.
// ---------------------------------------------------------------------------

template <bool EXACT>
__device__ __forceinline__ void run_seg(const float* __restrict__ fb,
                                        const float* __restrict__ trans,
                                        int ci, bool evenLane,
                                        int r0, int ngrp,
                                        float& sOut, int& oOut, float& q0Out) {
    // E rows in f16 pairs: Eh[c] = (exp(trans[ci][2c]), exp(trans[ci][2c+1]))
    h2 Eh[24];
    #pragma unroll
    for (int c = 0; c < 24; ++c) {
        float e0 = __expf(trans[ci * KK + 2 * c]);
        float e1 = __expf(trans[ci * KK + 2 * c + 1]);
        Eh[c] = (h2){(_Float16)e0, (_Float16)e1};
    }

    // packed-f16 broadcast state: EXACT -> e_START; warm-up -> all-ones
    int au[24];
    #pragma unroll
    for (int c = 0; c < 24; ++c)
        au[c] = EXACT ? ((c == 23) ? 0x00003C00 : 0) : 0x3C003C00;

    float s = 0.0f;
    int esum = 0;
    int eswm = 0;        // ledger at warm-up boundary (0 for EXACT)
    float q0 = 1.0f;     // lane-0 residual at warm-up boundary (unused EXACT)

    // feats prefetch: groups of 4 rows
    float fr[4];
    #pragma unroll
    for (int k = 0; k < 4; ++k) fr[k] = fb[(r0 + k) * KK + ci];

    const int WG = WARM / 4;
    for (int g = 0; g < ngrp; ++g) {
        float fn[4] = {0.f, 0.f, 0.f, 0.f};
        if (g < ngrp - 1) {
            #pragma unroll
            for (int k = 0; k < 4; ++k)
                fn[k] = fb[(r0 + (g + 1) * 4 + k) * KK + ci];
        }
        float ef[4];
        #pragma unroll
        for (int k = 0; k < 4; ++k) ef[k] = __expf(fr[k]);

        #pragma unroll
        for (int k = 0; k < 4; ++k) {
            // s_i = sum_c dot2(Eh[c], au[c]) : 4 chains x 6
            float a0 = 0.f, a1 = 0.f, a2 = 0.f, a3 = 0.f;
            #pragma unroll
            for (int c = 0; c < 6; ++c) {
                a0 = fdot2(Eh[4 * c + 0], __builtin_bit_cast(h2, au[4 * c + 0]), a0);
                a1 = fdot2(Eh[4 * c + 1], __builtin_bit_cast(h2, au[4 * c + 1]), a1);
                a2 = fdot2(Eh[4 * c + 2], __builtin_bit_cast(h2, au[4 * c + 2]), a2);
                a3 = fdot2(Eh[4 * c + 3], __builtin_bit_cast(h2, au[4 * c + 3]), a3);
            }
            float sr = ((a0 + a1) + (a2 + a3)) * ef[k];
            // uniform pow-2 rescale EVERY step (f16 range), exact int ledger
            int rl0 = __builtin_amdgcn_readlane(__float_as_int(sr), 0);
            int e0 = ((rl0 >> 23) & 0xff) - 127;
            esum += e0;
            s = sr * __int_as_float((127 - e0) << 23);
            // pack pair {s_2c, s_2c+1} via DPP partner swap, broadcast 24 dwords
            int pb = __builtin_amdgcn_update_dpp(
                0, __float_as_int(s), 0xB1, 0xF, 0xF, true);  // quad_perm 1,0,3,2
            float pv = __int_as_float(pb);
            float lo = evenLane ? s : pv;
            float hi = evenLane ? pv : s;
            int pkb = __builtin_bit_cast(int, __builtin_amdgcn_cvt_pkrtz(lo, hi));
            #pragma unroll
            for (int c = 0; c < 24; ++c)
                au[c] = __builtin_amdgcn_readlane(pkb, 2 * c);
        }

        if (!EXACT && g == WG - 1) {   // wave-uniform, taken once
            eswm = esum;
            q0 = __int_as_float(__builtin_amdgcn_readfirstlane(__float_as_int(s)));
        }

        #pragma unroll
        for (int k = 0; k < 4; ++k) fr[k] = fn[k];
    }
    sOut = s;                // residual direction at segment end (lane0 in [1,2))
    oOut = esum - eswm;      // exact owned-steps ledger
    q0Out = q0;
}

__global__ __launch_bounds__(NTHR)
__attribute__((amdgpu_waves_per_eu(8)))
void crf_kernel(const float* __restrict__ feats,
                const float* __restrict__ trans,
                const int* __restrict__ tags,
                float* __restrict__ out) {
    const int b = blockIdx.x;
    const int tid = threadIdx.x;
    const int wave = tid >> 6;          // segment index 0..NSEG-1
    const int lane = tid & 63;
    const int ci = (lane < KK) ? lane : 0;
    const bool evenLane = (lane & 1) == 0;
    const float* fb = feats + (size_t)b * TT * KK;
    const int* tg = tags + b * TT;

    __shared__ float shU[NSEG][64];   // final residual vectors
    __shared__ int shO[NSEG];         // owned ledgers
    __shared__ float shQ0[NSEG];      // lane-0 residual at warm-up boundary
    __shared__ float shGp[NSEG];      // gold partials

    float sF; int oW; float q0;
    if (wave == 0) run_seg<true >(fb, trans, ci, evenLane, 0, OWN / 4, sF, oW, q0);
    else           run_seg<false>(fb, trans, ci, evenLane,
                                  wave * OWN - WARM, (OWN + WARM) / 4, sF, oW, q0);

    shU[wave][lane] = sF;
    if (lane == 0) { shO[wave] = oW; shQ0[wave] = q0; }

    // ---- gold gather: 1024 t's over NTHR threads (after the hot loop) ----
    float gacc = 0.0f;
    #pragma unroll
    for (int r = 0; r < TT / NTHR; ++r) {
        int t = tid + r * NTHR;
        int cur = tg[t];
        int prev = (t == 0) ? START_TAG : tg[t - 1];
        gacc += trans[cur * KK + prev] + fb[(size_t)t * KK + cur];
    }
    #pragma unroll
    for (int off = 32; off; off >>= 1) gacc += __shfl_xor(gacc, off, 64);
    if (lane == 0) shGp[wave] = gacc;

    __syncthreads();

    if (tid < 64) {
        // Z-direction combine: sum_i exp(trans[END][i]) * u_{NSEG-1}[i]
        float val = (lane < KK) ? __expf(trans[END_TAG * KK + lane]) * shU[NSEG - 1][lane]
                                : 0.0f;
        #pragma unroll
        for (int off = 32; off; off >>= 1) val += __shfl_xor(val, off, 64);
        if (lane == 0) {
            int osum = 0;
            float gold = trans[END_TAG * KK + tg[TT - 1]];
            #pragma unroll
            for (int w = 0; w < NSEG; ++w) { osum += shO[w]; gold += shGp[w]; }
            float logz = __logf(val) + (float)osum * 0.6931471805599453f;
            // scalar stitches: alpha scale handoff across segment boundaries
            #pragma unroll
            for (int w = 1; w < NSEG; ++w)
                logz += __logf(shU[w - 1][0]) - __logf(shQ0[w]);
            out[b] = logz - gold;
        }
    }
}

extern "C" void kernel_launch(void* const* d_in, const int* in_sizes, int n_in,
                              void* d_out, int out_size, void* d_ws, size_t ws_size,
                              hipStream_t stream) {
    const float* feats = (const float*)d_in[0];
    const float* trans = (const float*)d_in[1];
    const int* tags = (const int*)d_in[2];
    float* out = (float*)d_out;

    crf_kernel<<<BB, NTHR, 0, stream>>>(feats, trans, tags, out);
}